// Round 3
// baseline (5425.028 us; speedup 1.0000x reference)
//
#include <hip/hip_runtime.h>
#include <math.h>

#define D_MODEL 4096
#define N_EXP   64
#define N_ROWS  16384          // 4 * 4096
#define LN_EPS  1e-5f
#define TM      32             // rows per block (8 per wave)
#define KC      64             // k-chunk
#define NCH     (D_MODEL / KC) // 64 chunks
#define NBLK    (N_ROWS / TM)  // 512 blocks

// ------------------------------------------------------------------
// ws layout (floats):
//   [0, 262144)        gWT[kg][e][4]: gWT[(kg*64+e)*4 + j] = W[e][4kg+j]*gamma[4kg+j]
//   [262144, 262208)   G[e] = sum_d gamma[d]*W[e][d]
//   [262208, 262272)   C[e] = sum_d beta[d]*W[e][d] + b[e]
//   [262272, 295040)   partials[NBLK][64] per-block mean_w sums (512*64)
// ------------------------------------------------------------------

typedef __attribute__((address_space(3))) void        lds_vp;
typedef const __attribute__((address_space(1))) void  g_vp;

__device__ __forceinline__ void gld_lds16(const float* g, float* l) {
  __builtin_amdgcn_global_load_lds((g_vp*)g, (lds_vp*)l, 16, 0, 0);
}

// --- prep 1: gWT transpose, grid 256 x 256 ---
__global__ __launch_bounds__(256) void prep_transpose(
    const float* __restrict__ W, const float* __restrict__ gamma,
    float* __restrict__ gWT)
{
  const int b = blockIdx.x, t = threadIdx.x;
  const int e = t & 63, kgl = t >> 6;
  const int kg = b * 4 + kgl;
  const int d0 = kg * 4;
  const float4 wv = *(const float4*)(W + (size_t)e * D_MODEL + d0);
  const float4 gv = *(const float4*)(gamma + d0);
  float4 p;
  p.x = wv.x * gv.x; p.y = wv.y * gv.y; p.z = wv.z * gv.z; p.w = wv.w * gv.w;
  *(float4*)(gWT + ((size_t)kg * 64 + e) * 4) = p;
}

// --- prep 2: G[e], C[e], grid 64 x 256 ---
__global__ __launch_bounds__(256) void prep_gc(
    const float* __restrict__ W, const float* __restrict__ gamma,
    const float* __restrict__ beta, const float* __restrict__ bias,
    float* __restrict__ G, float* __restrict__ C)
{
  const int e = blockIdx.x, t = threadIdx.x;
  float sg = 0.f, sb = 0.f;
#pragma unroll
  for (int i = 0; i < 4; ++i) {
    const int d = (i * 256 + t) * 4;
    const float4 wv = *(const float4*)(W + (size_t)e * D_MODEL + d);
    const float4 gv = *(const float4*)(gamma + d);
    const float4 bv = *(const float4*)(beta + d);
    sg += wv.x * gv.x + wv.y * gv.y + wv.z * gv.z + wv.w * gv.w;
    sb += wv.x * bv.x + wv.y * bv.y + wv.z * bv.z + wv.w * bv.w;
  }
#pragma unroll
  for (int o = 32; o > 0; o >>= 1) {
    sg += __shfl_xor(sg, o, 64);
    sb += __shfl_xor(sb, o, 64);
  }
  __shared__ float rg_[4], rb_[4];
  const int wid = t >> 6, ln = t & 63;
  if (ln == 0) { rg_[wid] = sg; rb_[wid] = sb; }
  __syncthreads();
  if (t == 0) {
    G[e] = rg_[0] + rg_[1] + rg_[2] + rg_[3];
    C[e] = rb_[0] + rb_[1] + rb_[2] + rb_[3] + bias[e];
  }
}

// stage W tile for chunk kb: wave w stages kg-groups w*4..w*4+3 (4 instrs/wave)
__device__ __forceinline__ void stage_w(
    const float* __restrict__ gWT, float* wbuf, int w, int lane, int kb)
{
#pragma unroll
  for (int i = 0; i < 4; ++i) {
    const int kgl = w * 4 + i;
    const float* gw = gWT + ((size_t)(kb / 4 + kgl) * 64 + lane) * 4;
    gld_lds16(gw, wbuf + kgl * 256);
  }
}

__global__ __launch_bounds__(256, 2) void router_main(
    const float* __restrict__ x, const float* __restrict__ gWT,
    const float* __restrict__ G, const float* __restrict__ C,
    float* __restrict__ out_sw, float* __restrict__ out_idx,
    float* __restrict__ out_partials, int k)
{
  __shared__ float wb[2][KC * N_EXP];  // 2 x 16 KB, [kg][e][4]
  __shared__ float mu_s[TM], rs_s[TM];

  const int t    = threadIdx.x;
  const int w    = t >> 6;        // wave id (0..3): rows w*8..w*8+7
  const int lane = t & 63;        // = expert index
  const int blk  = blockIdx.x;
  const size_t row0 = (size_t)blk * TM + w * 8;   // this wave's first row

  float acc[8];
#pragma unroll
  for (int r = 0; r < 8; ++r) acc[r] = 0.f;
  float Sp = 0.f, Qp = 0.f;
  // LN sweep mapping: lane -> (row = lane>>3, koff = (lane&7)*8)
  const float* xln = x + (row0 + (lane >> 3)) * D_MODEL + (lane & 7) * 8;

  stage_w(gWT, wb[0], w, lane, 0);

  for (int c = 0; c < NCH; ++c) {
    __syncthreads();                 // tile c resident (drains all waves' vmcnt)
    const float* wt = wb[c & 1];
    const float* xr = x + row0 * D_MODEL + c * KC;

    // LN loads early (consumed late in the chunk -> latency hidden)
    const float4 l0 = *(const float4*)(xln + c * KC);
    const float4 l1 = *(const float4*)(xln + c * KC + 4);

    // GEMM: x via VMEM broadcast (L1/L2-hit), W via 16 ds_read_b128
#pragma unroll
    for (int kg = 0; kg < 16; ++kg) {
      const float4 wv = *(const float4*)(wt + kg * 256 + lane * 4);  // conflict-free
#pragma unroll
      for (int r = 0; r < 8; ++r) {
        const float4 xv = *(const float4*)(xr + (size_t)r * D_MODEL + kg * 4);  // broadcast
        acc[r] = fmaf(xv.x, wv.x, fmaf(xv.y, wv.y, fmaf(xv.z, wv.z, fmaf(xv.w, wv.w, acc[r]))));
      }
    }

    // LN stats accumulate
    Sp += l0.x + l0.y + l0.z + l0.w + l1.x + l1.y + l1.z + l1.w;
    Qp = fmaf(l0.x, l0.x, Qp); Qp = fmaf(l0.y, l0.y, Qp);
    Qp = fmaf(l0.z, l0.z, Qp); Qp = fmaf(l0.w, l0.w, Qp);
    Qp = fmaf(l1.x, l1.x, Qp); Qp = fmaf(l1.y, l1.y, Qp);
    Qp = fmaf(l1.z, l1.z, Qp); Qp = fmaf(l1.w, l1.w, Qp);

    // prefetch W for c+1 LAST: its vmcnt drain happens at the next barrier,
    // never on this chunk's compute x-loads (vmcnt waits are oldest-first).
    if (c + 1 < NCH) stage_w(gWT, wb[(c + 1) & 1], w, lane, (c + 1) * KC);
  }

  // reduce S/Q across the 8 lanes sharing a row (xor bits 0..2)
#pragma unroll
  for (int o = 1; o < 8; o <<= 1) {
    Sp += __shfl_xor(Sp, o, 64);
    Qp += __shfl_xor(Qp, o, 64);
  }
  if ((lane & 7) == 0) {
    const int rl  = w * 8 + (lane >> 3);
    const float mu  = Sp * (1.f / D_MODEL);
    const float var = Qp * (1.f / D_MODEL) - mu * mu;
    mu_s[rl] = mu;
    rs_s[rl] = rsqrtf(var + LN_EPS);
  }
  __syncthreads();

  // epilogue: lane = expert; acc[r] is the raw dot(x_row, gW_e)
  const float Gv = G[lane];
  const float Cv = C[lane];
  float mw = 0.f;
  for (int r = 0; r < 8; ++r) {
    const int rl = w * 8 + r;
    const size_t row = (size_t)blk * TM + rl;
    const float l = rs_s[rl] * (acc[r] - mu_s[rl] * Gv) + Cv;
    float m = l;
#pragma unroll
    for (int o = 32; o > 0; o >>= 1) m = fmaxf(m, __shfl_xor(m, o, 64));
    const float p = __expf(l - m);
    float s = p;
#pragma unroll
    for (int o = 32; o > 0; o >>= 1) s += __shfl_xor(s, o, 64);
    const float wv = p / s;
    mw += wv;

    float rem = wv, denom = 0.f, myval = 0.f;
    for (int j = 0; j < k; ++j) {
      float mx = rem;
#pragma unroll
      for (int o = 32; o > 0; o >>= 1) mx = fmaxf(mx, __shfl_xor(mx, o, 64));
      const unsigned long long ball = __ballot(rem == mx);
      const int ie = __ffsll((long long)ball) - 1;   // lowest index on ties (jax semantics)
      denom += mx;
      if (lane == ie) { myval = wv; rem = -1.f; }
      if (lane == j) out_idx[row * k + j] = (float)ie;
    }
    out_sw[row * N_EXP + lane] = myval / (denom + 1e-8f);
  }

  // per-block mean_w partial (deterministic)
  __syncthreads();
  float* red = wb[0];
  red[t] = mw;
  __syncthreads();
  if (t < 64)
    out_partials[blk * 64 + t] = red[t] + red[64 + t] + red[128 + t] + red[192 + t];
}

__global__ __launch_bounds__(256) void loss_kernel(
    const float* __restrict__ partials, float* __restrict__ out_loss)
{
  const int t = threadIdx.x, e = t & 63, q = t >> 6;
  float s = 0.f;
#pragma unroll 8
  for (int b = 0; b < 128; ++b) s += partials[(q * 128 + b) * 64 + e];
  __shared__ float sh[256];
  sh[t] = s;
  __syncthreads();
  if (t < 64) {
    const float m = (sh[t] + sh[64 + t] + sh[128 + t] + sh[192 + t]) * (1.f / N_ROWS);
    float v = -m * logf(m + 1e-8f);
#pragma unroll
    for (int o = 32; o > 0; o >>= 1) v += __shfl_xor(v, o, 64);
    if (t == 0) out_loss[0] = v;
  }
}

extern "C" void kernel_launch(void* const* d_in, const int* in_sizes, int n_in,
                              void* d_out, int out_size, void* d_ws, size_t ws_size,
                              hipStream_t stream)
{
  const float* x     = (const float*)d_in[0];
  const float* gamma = (const float*)d_in[1];
  const float* beta  = (const float*)d_in[2];
  const float* W     = (const float*)d_in[3];
  const float* bias  = (const float*)d_in[4];

  float* ws       = (float*)d_ws;
  float* gWT      = ws;
  float* G        = ws + 262144;
  float* C        = ws + 262208;
  float* partials = ws + 262272;

  int k = (out_size - N_ROWS * N_EXP - 1) / N_ROWS;
  if (k < 1) k = 1;
  if (k > 8) k = 8;

  float* out      = (float*)d_out;
  float* out_sw   = out;
  float* out_idx  = out + (size_t)N_ROWS * N_EXP;
  float* out_loss = out + (size_t)N_ROWS * N_EXP + (size_t)N_ROWS * k;

  hipLaunchKernelGGL(prep_transpose, dim3(256), dim3(256), 0, stream, W, gamma, gWT);
  hipLaunchKernelGGL(prep_gc, dim3(N_EXP), dim3(256), 0, stream, W, gamma, beta, bias, G, C);
  hipLaunchKernelGGL(router_main, dim3(NBLK), dim3(256), 0, stream,
                     x, gWT, G, C, out_sw, out_idx, partials, k);
  hipLaunchKernelGGL(loss_kernel, dim3(1), dim3(256), 0, stream, partials, out_loss);
}

// Round 4
// 560.495 us; speedup vs baseline: 9.6790x; 9.6790x over previous
//
#include <hip/hip_runtime.h>
#include <math.h>

#define D_MODEL 4096
#define N_EXP   64
#define N_ROWS  16384            // 4 * 4096
#define LN_EPS  1e-5f
#define TMB     64               // rows per block (16 per wave)
#define NBLK    (N_ROWS / TMB)   // 256 blocks

typedef __attribute__((ext_vector_type(4))) float f32x4;
typedef __attribute__((ext_vector_type(8))) short s16x8;

struct U4 { unsigned v[4]; };

// truncating bf16 split helpers: pkt packs hi16(a) | hi16(b); residuals are exact.
__device__ __forceinline__ unsigned pkt(float a, float b) {
  unsigned ua = __builtin_bit_cast(unsigned, a);
  unsigned ub = __builtin_bit_cast(unsigned, b);
  return (ua >> 16) | (ub & 0xffff0000u);
}
__device__ __forceinline__ float lo2f(unsigned p) { return __builtin_bit_cast(float, p << 16); }
__device__ __forceinline__ float hi2f(unsigned p) { return __builtin_bit_cast(float, p & 0xffff0000u); }

// split 8 fp32 -> 3 bf16x8 fragments (h1+h2+h3 capture >=23 mantissa bits)
__device__ __forceinline__ void split8(const float* f, U4& u1, U4& u2, U4& u3) {
#pragma unroll
  for (int i = 0; i < 4; ++i) {
    const float a = f[2 * i], b = f[2 * i + 1];
    const unsigned p1 = pkt(a, b);
    const float ra = a - lo2f(p1), rb = b - hi2f(p1);
    const unsigned p2 = pkt(ra, rb);
    const float sa = ra - lo2f(p2), sb = rb - hi2f(p2);
    u1.v[i] = p1; u2.v[i] = p2; u3.v[i] = pkt(sa, sb);
  }
}

// ------------------------------------------------------------------
// ws layout (floats):
//   [0, 393216)        Bpre: frag (kb32, j0, term, lane) -> bf16x8, 16 B each
//                      addr_f32 = ((kb32*12 + j0*3 + term)*64 + lane)*4
//   [393216, 393280)   G[e] = sum_d gamma[d]*W[e][d]
//   [393280, 393344)   C[e] = sum_d beta[d]*W[e][d] + b[e]
//   [393344, 409728)   partials[NBLK][64]
// ------------------------------------------------------------------

__global__ __launch_bounds__(64) void prep_bpre(
    const float* __restrict__ W, const float* __restrict__ gamma,
    float* __restrict__ Bpre)
{
  const int b = blockIdx.x;            // 0..511
  const int kb32 = b >> 2, j0 = b & 3;
  const int L = threadIdx.x, q = L >> 4, c = L & 15;
  const int n  = j0 * 16 + c;          // expert
  const int k0 = kb32 * 32 + q * 8;    // k offset
  const float4 w0 = *(const float4*)(W + (size_t)n * D_MODEL + k0);
  const float4 w1 = *(const float4*)(W + (size_t)n * D_MODEL + k0 + 4);
  const float4 g0 = *(const float4*)(gamma + k0);
  const float4 g1 = *(const float4*)(gamma + k0 + 4);
  float f[8] = {w0.x * g0.x, w0.y * g0.y, w0.z * g0.z, w0.w * g0.w,
                w1.x * g1.x, w1.y * g1.y, w1.z * g1.z, w1.w * g1.w};
  U4 u1, u2, u3;
  split8(f, u1, u2, u3);
  const size_t base = ((size_t)kb32 * 12 + j0 * 3) * 64 + L;
  *(float4*)(Bpre + (base + 0 * 64) * 4) = __builtin_bit_cast(float4, u1);
  *(float4*)(Bpre + (base + 1 * 64) * 4) = __builtin_bit_cast(float4, u2);
  *(float4*)(Bpre + (base + 2 * 64) * 4) = __builtin_bit_cast(float4, u3);
}

__global__ __launch_bounds__(256) void prep_gc(
    const float* __restrict__ W, const float* __restrict__ gamma,
    const float* __restrict__ beta, const float* __restrict__ bias,
    float* __restrict__ G, float* __restrict__ C)
{
  const int e = blockIdx.x, t = threadIdx.x;
  float sg = 0.f, sb = 0.f;
#pragma unroll
  for (int i = 0; i < 4; ++i) {
    const int d = (i * 256 + t) * 4;
    const float4 wv = *(const float4*)(W + (size_t)e * D_MODEL + d);
    const float4 gv = *(const float4*)(gamma + d);
    const float4 bv = *(const float4*)(beta + d);
    sg += wv.x * gv.x + wv.y * gv.y + wv.z * gv.z + wv.w * gv.w;
    sb += wv.x * bv.x + wv.y * bv.y + wv.z * bv.z + wv.w * bv.w;
  }
#pragma unroll
  for (int o = 32; o > 0; o >>= 1) {
    sg += __shfl_xor(sg, o, 64);
    sb += __shfl_xor(sb, o, 64);
  }
  __shared__ float rg_[4], rb_[4];
  const int wid = t >> 6, ln = t & 63;
  if (ln == 0) { rg_[wid] = sg; rb_[wid] = sb; }
  __syncthreads();
  if (t == 0) {
    G[e] = rg_[0] + rg_[1] + rg_[2] + rg_[3];
    C[e] = rb_[0] + rb_[1] + rb_[2] + rb_[3] + bias[e];
  }
}

__global__ __launch_bounds__(256, 1) void router_main(
    const float* __restrict__ x, const float* __restrict__ Bpre,
    const float* __restrict__ G, const float* __restrict__ C,
    float* __restrict__ out_sw, float* __restrict__ out_idx,
    float* __restrict__ out_partials, int k)
{
  const int t = threadIdx.x, w = t >> 6, L = t & 63;
  const int q = L >> 4, c = L & 15;
  const int blk = blockIdx.x;
  const int row0 = blk * TMB + w * 16;

  // A-frag source: lane holds rows row0+c, k-offsets q*8.. (MFMA A layout)
  const float* aptr = x + (size_t)(row0 + c) * D_MODEL + q * 8;

  f32x4 acc[4];
#pragma unroll
  for (int j0 = 0; j0 < 4; ++j0) acc[j0] = (f32x4){0.f, 0.f, 0.f, 0.f};
  float Sp = 0.f, Qp = 0.f;

  float4 Abuf[2][8];
  // preload outer chunk 0
#pragma unroll
  for (int s = 0; s < 4; ++s) {
    Abuf[0][2 * s]     = *(const float4*)(aptr + s * 32);
    Abuf[0][2 * s + 1] = *(const float4*)(aptr + s * 32 + 4);
  }

  const int PA[6] = {0, 0, 1, 0, 1, 2};   // products (i,j) with i+j<=4
  const int PB[6] = {0, 1, 0, 2, 1, 0};

  for (int kb = 0; kb < 32; ++kb) {
    { // prefetch A for kb+1 (issued first -> oldest in vmcnt queue, consumed first next iter)
      const int nb = (kb + 1 < 32) ? kb + 1 : 0;
      const float* ap = aptr + nb * 128;
      float4* An = Abuf[(kb + 1) & 1];
#pragma unroll
      for (int s = 0; s < 4; ++s) {
        An[2 * s]     = *(const float4*)(ap + s * 32);
        An[2 * s + 1] = *(const float4*)(ap + s * 32 + 4);
      }
    }
    const float4* Ac = Abuf[kb & 1];
#pragma unroll
    for (int s = 0; s < 4; ++s) {
      const int kb32 = kb * 4 + s;
      // B fragments for this 32-chunk (pre-split, already in MFMA operand layout; L1/L2-hit)
      s16x8 bf[4][3];
#pragma unroll
      for (int j0 = 0; j0 < 4; ++j0)
#pragma unroll
        for (int tt = 0; tt < 3; ++tt) {
          const float4 bv = *(const float4*)(Bpre + (((size_t)kb32 * 12 + j0 * 3 + tt) * 64 + L) * 4);
          bf[j0][tt] = __builtin_bit_cast(s16x8, bv);
        }
      // convert A + LN stats
      const float4 a0 = Ac[2 * s], a1 = Ac[2 * s + 1];
      const float f[8] = {a0.x, a0.y, a0.z, a0.w, a1.x, a1.y, a1.z, a1.w};
#pragma unroll
      for (int i = 0; i < 8; ++i) { Sp += f[i]; Qp = fmaf(f[i], f[i], Qp); }
      U4 u1, u2, u3;
      split8(f, u1, u2, u3);
      const s16x8 af[3] = {__builtin_bit_cast(s16x8, u1),
                           __builtin_bit_cast(s16x8, u2),
                           __builtin_bit_cast(s16x8, u3)};
#pragma unroll
      for (int p = 0; p < 6; ++p)
#pragma unroll
        for (int j0 = 0; j0 < 4; ++j0)
          acc[j0] = __builtin_amdgcn_mfma_f32_16x16x32_bf16(af[PA[p]], bf[j0][PB[p]], acc[j0], 0, 0, 0);
    }
  }

  // ---- LN stats finalize: reduce over the 4 lanes (q) sharing a row ----
#pragma unroll
  for (int o = 16; o <= 32; o <<= 1) {
    Sp += __shfl_xor(Sp, o, 64);
    Qp += __shfl_xor(Qp, o, 64);
  }
  const float mu = Sp * (1.f / D_MODEL);
  const float rs = rsqrtf(Qp * (1.f / D_MODEL) - mu * mu + LN_EPS);  // lane L: stats of row row0+c

  float Gv[4], Cv[4];
#pragma unroll
  for (int j0 = 0; j0 < 4; ++j0) { Gv[j0] = G[16 * j0 + c]; Cv[j0] = C[16 * j0 + c]; }

  float mw[4] = {0.f, 0.f, 0.f, 0.f};
#pragma unroll
  for (int i = 0; i < 4; ++i) {          // row phase: this lane group handles row 4q+i
    const int rloc = 4 * q + i;
    const int row  = row0 + rloc;
    const float mui = __shfl(mu, rloc, 64);   // stats live at lane==row index (c=rloc,q=0 copy)
    const float rsi = __shfl(rs, rloc, 64);
    float l[4];
#pragma unroll
    for (int j0 = 0; j0 < 4; ++j0)
      l[j0] = rsi * (acc[j0][i] - mui * Gv[j0]) + Cv[j0];
    float mx = fmaxf(fmaxf(l[0], l[1]), fmaxf(l[2], l[3]));
#pragma unroll
    for (int o = 1; o < 16; o <<= 1) mx = fmaxf(mx, __shfl_xor(mx, o, 64));
    float p[4], ss = 0.f;
#pragma unroll
    for (int j0 = 0; j0 < 4; ++j0) { p[j0] = __expf(l[j0] - mx); ss += p[j0]; }
#pragma unroll
    for (int o = 1; o < 16; o <<= 1) ss += __shfl_xor(ss, o, 64);
    float wv[4];
#pragma unroll
    for (int j0 = 0; j0 < 4; ++j0) { wv[j0] = p[j0] / ss; mw[j0] += wv[j0]; }

    // top-k (lowest-index tie-break, matches jax.lax.top_k)
    int ch[4];
    float denom = 0.f;
    for (int kk = 0; kk < k && kk < 4; ++kk) {
      float vb = -1.f; int eb = 1 << 30;
#pragma unroll
      for (int j0 = 0; j0 < 4; ++j0) {
        const int e = 16 * j0 + c;
        bool skip = false;
        for (int z = 0; z < kk; ++z) skip |= (ch[z] == e);
        const float cand = skip ? -1.f : wv[j0];
        if (cand > vb || (cand == vb && e < eb)) { vb = cand; eb = e; }
      }
#pragma unroll
      for (int o = 1; o < 16; o <<= 1) {
        const float ov = __shfl_xor(vb, o, 64);
        const int   oe = __shfl_xor(eb, o, 64);
        if (ov > vb || (ov == vb && oe < eb)) { vb = ov; eb = oe; }
      }
      ch[kk] = eb; denom += vb;
      if (c == 0) out_idx[(size_t)row * k + kk] = (float)eb;
    }
    denom += 1e-8f;
#pragma unroll
    for (int j0 = 0; j0 < 4; ++j0) {
      const int e = 16 * j0 + c;
      bool sel = false;
      for (int z = 0; z < k && z < 4; ++z) sel |= (ch[z] == e);
      out_sw[(size_t)row * N_EXP + e] = sel ? wv[j0] / denom : 0.f;
    }
  }

  // ---- mean_w partials: sum over the wave's 16 rows (xor over q), then block ----
#pragma unroll
  for (int j0 = 0; j0 < 4; ++j0)
#pragma unroll
    for (int o = 16; o <= 32; o <<= 1) mw[j0] += __shfl_xor(mw[j0], o, 64);
  __shared__ float sm[4][64];
  if (q == 0) {
#pragma unroll
    for (int j0 = 0; j0 < 4; ++j0) sm[w][16 * j0 + c] = mw[j0];
  }
  __syncthreads();
  if (t < 64)
    out_partials[blk * 64 + t] = sm[0][t] + sm[1][t] + sm[2][t] + sm[3][t];
}

__global__ __launch_bounds__(256) void loss_kernel(
    const float* __restrict__ partials, float* __restrict__ out_loss)
{
  const int t = threadIdx.x, e = t & 63, qq = t >> 6;
  float s = 0.f;
#pragma unroll 8
  for (int b = 0; b < 64; ++b) s += partials[(qq * 64 + b) * 64 + e];
  __shared__ float sh[256];
  sh[t] = s;
  __syncthreads();
  if (t < 64) {
    const float m = (sh[t] + sh[64 + t] + sh[128 + t] + sh[192 + t]) * (1.f / N_ROWS);
    float v = -m * logf(m + 1e-8f);
#pragma unroll
    for (int o = 32; o > 0; o >>= 1) v += __shfl_xor(v, o, 64);
    if (t == 0) out_loss[0] = v;
  }
}

extern "C" void kernel_launch(void* const* d_in, const int* in_sizes, int n_in,
                              void* d_out, int out_size, void* d_ws, size_t ws_size,
                              hipStream_t stream)
{
  const float* x     = (const float*)d_in[0];
  const float* gamma = (const float*)d_in[1];
  const float* beta  = (const float*)d_in[2];
  const float* W     = (const float*)d_in[3];
  const float* bias  = (const float*)d_in[4];

  float* ws       = (float*)d_ws;
  float* Bpre     = ws;
  float* G        = ws + 393216;
  float* C        = ws + 393280;
  float* partials = ws + 393344;

  int k = (out_size - N_ROWS * N_EXP - 1) / N_ROWS;
  if (k < 1) k = 1;
  if (k > 4) k = 4;

  float* out      = (float*)d_out;
  float* out_sw   = out;
  float* out_idx  = out + (size_t)N_ROWS * N_EXP;
  float* out_loss = out + (size_t)N_ROWS * N_EXP + (size_t)N_ROWS * k;

  hipLaunchKernelGGL(prep_bpre, dim3(512), dim3(64), 0, stream, W, gamma, Bpre);
  hipLaunchKernelGGL(prep_gc, dim3(N_EXP), dim3(256), 0, stream, W, gamma, beta, bias, G, C);
  hipLaunchKernelGGL(router_main, dim3(NBLK), dim3(256), 0, stream,
                     x, Bpre, G, C, out_sw, out_idx, partials, k);
  hipLaunchKernelGGL(loss_kernel, dim3(1), dim3(256), 0, stream, partials, out_loss);
}

// Round 5
// 506.746 us; speedup vs baseline: 10.7056x; 1.1061x over previous
//
#include <hip/hip_runtime.h>
#include <math.h>

#define D_MODEL 4096
#define N_EXP   64
#define N_ROWS  16384            // 4 * 4096
#define LN_EPS  1e-5f
#define TMB     64               // rows per block (16 per wave)
#define NBLK    (N_ROWS / TMB)   // 256 blocks

typedef __attribute__((ext_vector_type(4))) float f32x4;
typedef __attribute__((ext_vector_type(8))) short s16x8;

struct U4 { unsigned v[4]; };

// truncating bf16 split helpers: pkt packs hi16(a) | hi16(b); residuals are exact.
__device__ __forceinline__ unsigned pkt(float a, float b) {
  unsigned ua = __builtin_bit_cast(unsigned, a);
  unsigned ub = __builtin_bit_cast(unsigned, b);
  return (ua >> 16) | (ub & 0xffff0000u);
}
__device__ __forceinline__ float lo2f(unsigned p) { return __builtin_bit_cast(float, p << 16); }
__device__ __forceinline__ float hi2f(unsigned p) { return __builtin_bit_cast(float, p & 0xffff0000u); }

// split 8 fp32 -> 3 bf16x8 fragments (h1+h2+h3 capture >=23 mantissa bits)
__device__ __forceinline__ void split8(const float* f, U4& u1, U4& u2, U4& u3) {
#pragma unroll
  for (int i = 0; i < 4; ++i) {
    const float a = f[2 * i], b = f[2 * i + 1];
    const unsigned p1 = pkt(a, b);
    const float ra = a - lo2f(p1), rb = b - hi2f(p1);
    const unsigned p2 = pkt(ra, rb);
    const float sa = ra - lo2f(p2), sb = rb - hi2f(p2);
    u1.v[i] = p1; u2.v[i] = p2; u3.v[i] = pkt(sa, sb);
  }
}

// ------------------------------------------------------------------
// ws layout (floats):
//   [0, 393216)        Bpre: frag (kb32, j0, term, lane) -> bf16x8, 16 B each
//   [393216, 393280)   G[e] = sum_d gamma[d]*W[e][d]
//   [393280, 393344)   C[e] = sum_d beta[d]*W[e][d] + b[e]
//   [393344, 409728)   partials[NBLK][64]
// ------------------------------------------------------------------

__global__ __launch_bounds__(64) void prep_bpre(
    const float* __restrict__ W, const float* __restrict__ gamma,
    float* __restrict__ Bpre)
{
  const int b = blockIdx.x;            // 0..511
  const int kb32 = b >> 2, j0 = b & 3;
  const int L = threadIdx.x, q = L >> 4, c = L & 15;
  const int n  = j0 * 16 + c;          // expert
  const int k0 = kb32 * 32 + q * 8;    // k offset
  const float4 w0 = *(const float4*)(W + (size_t)n * D_MODEL + k0);
  const float4 w1 = *(const float4*)(W + (size_t)n * D_MODEL + k0 + 4);
  const float4 g0 = *(const float4*)(gamma + k0);
  const float4 g1 = *(const float4*)(gamma + k0 + 4);
  float f[8] = {w0.x * g0.x, w0.y * g0.y, w0.z * g0.z, w0.w * g0.w,
                w1.x * g1.x, w1.y * g1.y, w1.z * g1.z, w1.w * g1.w};
  U4 u1, u2, u3;
  split8(f, u1, u2, u3);
  const size_t base = ((size_t)kb32 * 12 + j0 * 3) * 64 + L;
  *(float4*)(Bpre + (base + 0 * 64) * 4) = __builtin_bit_cast(float4, u1);
  *(float4*)(Bpre + (base + 1 * 64) * 4) = __builtin_bit_cast(float4, u2);
  *(float4*)(Bpre + (base + 2 * 64) * 4) = __builtin_bit_cast(float4, u3);
}

__global__ __launch_bounds__(256) void prep_gc(
    const float* __restrict__ W, const float* __restrict__ gamma,
    const float* __restrict__ beta, const float* __restrict__ bias,
    float* __restrict__ G, float* __restrict__ C)
{
  const int e = blockIdx.x, t = threadIdx.x;
  float sg = 0.f, sb = 0.f;
#pragma unroll
  for (int i = 0; i < 4; ++i) {
    const int d = (i * 256 + t) * 4;
    const float4 wv = *(const float4*)(W + (size_t)e * D_MODEL + d);
    const float4 gv = *(const float4*)(gamma + d);
    const float4 bv = *(const float4*)(beta + d);
    sg += wv.x * gv.x + wv.y * gv.y + wv.z * gv.z + wv.w * gv.w;
    sb += wv.x * bv.x + wv.y * bv.y + wv.z * bv.z + wv.w * bv.w;
  }
#pragma unroll
  for (int o = 32; o > 0; o >>= 1) {
    sg += __shfl_xor(sg, o, 64);
    sb += __shfl_xor(sb, o, 64);
  }
  __shared__ float rg_[4], rb_[4];
  const int wid = t >> 6, ln = t & 63;
  if (ln == 0) { rg_[wid] = sg; rb_[wid] = sb; }
  __syncthreads();
  if (t == 0) {
    G[e] = rg_[0] + rg_[1] + rg_[2] + rg_[3];
    C[e] = rb_[0] + rb_[1] + rb_[2] + rb_[3] + bias[e];
  }
}

__device__ __forceinline__ void loadA(const float* aptr, int kb, float4 A[8]) {
  const float* ap = aptr + (size_t)kb * 128;
#pragma unroll
  for (int s = 0; s < 4; ++s) {
    A[2 * s]     = *(const float4*)(ap + s * 32);
    A[2 * s + 1] = *(const float4*)(ap + s * 32 + 4);
  }
}

__device__ __forceinline__ void loadB(const float* __restrict__ Bpre, int kb32, int L,
                                      s16x8 bf[4][3]) {
#pragma unroll
  for (int j0 = 0; j0 < 4; ++j0)
#pragma unroll
    for (int tt = 0; tt < 3; ++tt) {
      const float4 bv = *(const float4*)(Bpre + (((size_t)kb32 * 12 + j0 * 3 + tt) * 64 + L) * 4);
      bf[j0][tt] = __builtin_bit_cast(s16x8, bv);
    }
}

// one 128-k chunk: compute with Acur, prefetch next A into Anext.
// Ordering: B(s0) loads first, then the A prefetch (younger in the vmcnt
// queue -> B consumption never drains it), then B(s+1) pipelined vs compute.
__device__ __forceinline__ void compute_chunk(
    const float* __restrict__ Bpre, const float* aptr, int kb, int next_kb, int L,
    const float4 Acur[8], float4 Anext[8], f32x4 acc[4], float& Sp, float& Qp)
{
  const int PA[6] = {0, 0, 1, 0, 1, 2};
  const int PB[6] = {0, 1, 0, 2, 1, 0};
  s16x8 bf[2][4][3];
  loadB(Bpre, kb * 4, L, bf[0]);
  loadA(aptr, next_kb, Anext);
#pragma unroll
  for (int s = 0; s < 4; ++s) {
    if (s < 3) loadB(Bpre, kb * 4 + s + 1, L, bf[(s + 1) & 1]);
    const float4 a0 = Acur[2 * s], a1 = Acur[2 * s + 1];
    const float f[8] = {a0.x, a0.y, a0.z, a0.w, a1.x, a1.y, a1.z, a1.w};
#pragma unroll
    for (int i = 0; i < 8; ++i) { Sp += f[i]; Qp = fmaf(f[i], f[i], Qp); }
    U4 u1, u2, u3;
    split8(f, u1, u2, u3);
    const s16x8 af[3] = {__builtin_bit_cast(s16x8, u1),
                         __builtin_bit_cast(s16x8, u2),
                         __builtin_bit_cast(s16x8, u3)};
#pragma unroll
    for (int p = 0; p < 6; ++p)
#pragma unroll
      for (int j0 = 0; j0 < 4; ++j0)
        acc[j0] = __builtin_amdgcn_mfma_f32_16x16x32_bf16(af[PA[p]], bf[s & 1][j0][PB[p]],
                                                          acc[j0], 0, 0, 0);
  }
}

__global__ __launch_bounds__(256, 1) void router_main(
    const float* __restrict__ x, const float* __restrict__ Bpre,
    const float* __restrict__ G, const float* __restrict__ C,
    float* __restrict__ out_sw, float* __restrict__ out_idx,
    float* __restrict__ out_partials, int k)
{
  const int t = threadIdx.x, w = t >> 6, L = t & 63;
  const int q = L >> 4, c = L & 15;
  const int blk = blockIdx.x;
  const int row0 = blk * TMB + w * 16;

  // A-frag source (MFMA A layout): lane holds row row0+c, k-offsets q*8+0..7
  const float* aptr = x + (size_t)(row0 + c) * D_MODEL + q * 8;

  f32x4 acc[4];
#pragma unroll
  for (int j0 = 0; j0 < 4; ++j0) acc[j0] = (f32x4){0.f, 0.f, 0.f, 0.f};
  float Sp = 0.f, Qp = 0.f;

  float4 A0[8], A1[8];          // named buffers, ALL indices compile-time
  loadA(aptr, 0, A0);

  for (int kb = 0; kb < 32; kb += 2) {
    compute_chunk(Bpre, aptr, kb,     kb + 1,              L, A0, A1, acc, Sp, Qp);
    compute_chunk(Bpre, aptr, kb + 1, (kb + 2) & 31,       L, A1, A0, acc, Sp, Qp);
  }

  // ---- LN stats finalize: reduce over the 4 lanes (q) sharing a row ----
#pragma unroll
  for (int o = 16; o <= 32; o <<= 1) {
    Sp += __shfl_xor(Sp, o, 64);
    Qp += __shfl_xor(Qp, o, 64);
  }
  const float mu = Sp * (1.f / D_MODEL);
  const float rs = rsqrtf(Qp * (1.f / D_MODEL) - mu * mu + LN_EPS);  // stats of row row0+c

  float Gv[4], Cv[4];
#pragma unroll
  for (int j0 = 0; j0 < 4; ++j0) { Gv[j0] = G[16 * j0 + c]; Cv[j0] = C[16 * j0 + c]; }

  float mw[4] = {0.f, 0.f, 0.f, 0.f};
#pragma unroll
  for (int i = 0; i < 4; ++i) {          // C-layout: row = 4q+i, col = c
    const int rloc = 4 * q + i;
    const int row  = row0 + rloc;
    const float mui = __shfl(mu, rloc, 64);
    const float rsi = __shfl(rs, rloc, 64);
    float l[4];
#pragma unroll
    for (int j0 = 0; j0 < 4; ++j0)
      l[j0] = rsi * (acc[j0][i] - mui * Gv[j0]) + Cv[j0];
    float mx = fmaxf(fmaxf(l[0], l[1]), fmaxf(l[2], l[3]));
#pragma unroll
    for (int o = 1; o < 16; o <<= 1) mx = fmaxf(mx, __shfl_xor(mx, o, 64));
    float p[4], ss = 0.f;
#pragma unroll
    for (int j0 = 0; j0 < 4; ++j0) { p[j0] = __expf(l[j0] - mx); ss += p[j0]; }
#pragma unroll
    for (int o = 1; o < 16; o <<= 1) ss += __shfl_xor(ss, o, 64);
    float wv[4];
#pragma unroll
    for (int j0 = 0; j0 < 4; ++j0) { wv[j0] = p[j0] / ss; mw[j0] += wv[j0]; }

    // top-k (lowest-index tie-break, matches jax.lax.top_k)
    int ch[4];
    float denom = 0.f;
    for (int kk = 0; kk < k && kk < 4; ++kk) {
      float vb = -1.f; int eb = 1 << 30;
#pragma unroll
      for (int j0 = 0; j0 < 4; ++j0) {
        const int e = 16 * j0 + c;
        bool skip = false;
        for (int z = 0; z < kk; ++z) skip |= (ch[z] == e);
        const float cand = skip ? -1.f : wv[j0];
        if (cand > vb || (cand == vb && e < eb)) { vb = cand; eb = e; }
      }
#pragma unroll
      for (int o = 1; o < 16; o <<= 1) {
        const float ov = __shfl_xor(vb, o, 64);
        const int   oe = __shfl_xor(eb, o, 64);
        if (ov > vb || (ov == vb && oe < eb)) { vb = ov; eb = oe; }
      }
      ch[kk] = eb; denom += vb;
      if (c == 0) out_idx[(size_t)row * k + kk] = (float)eb;
    }
    denom += 1e-8f;
#pragma unroll
    for (int j0 = 0; j0 < 4; ++j0) {
      const int e = 16 * j0 + c;
      bool sel = false;
      for (int z = 0; z < k && z < 4; ++z) sel |= (ch[z] == e);
      out_sw[(size_t)row * N_EXP + e] = sel ? wv[j0] / denom : 0.f;
    }
  }

  // ---- mean_w partials: sum over the wave's 16 rows (xor over q), then block ----
#pragma unroll
  for (int j0 = 0; j0 < 4; ++j0)
#pragma unroll
    for (int o = 16; o <= 32; o <<= 1) mw[j0] += __shfl_xor(mw[j0], o, 64);
  __shared__ float sm[4][64];
  if (q == 0) {
#pragma unroll
    for (int j0 = 0; j0 < 4; ++j0) sm[w][16 * j0 + c] = mw[j0];
  }
  __syncthreads();
  if (t < 64)
    out_partials[blk * 64 + t] = sm[0][t] + sm[1][t] + sm[2][t] + sm[3][t];
}

__global__ __launch_bounds__(256) void loss_kernel(
    const float* __restrict__ partials, float* __restrict__ out_loss)
{
  const int t = threadIdx.x, e = t & 63, qq = t >> 6;
  float s = 0.f;
#pragma unroll 8
  for (int b = 0; b < 64; ++b) s += partials[(qq * 64 + b) * 64 + e];
  __shared__ float sh[256];
  sh[t] = s;
  __syncthreads();
  if (t < 64) {
    const float m = (sh[t] + sh[64 + t] + sh[128 + t] + sh[192 + t]) * (1.f / N_ROWS);
    float v = -m * logf(m + 1e-8f);
#pragma unroll
    for (int o = 32; o > 0; o >>= 1) v += __shfl_xor(v, o, 64);
    if (t == 0) out_loss[0] = v;
  }
}

extern "C" void kernel_launch(void* const* d_in, const int* in_sizes, int n_in,
                              void* d_out, int out_size, void* d_ws, size_t ws_size,
                              hipStream_t stream)
{
  const float* x     = (const float*)d_in[0];
  const float* gamma = (const float*)d_in[1];
  const float* beta  = (const float*)d_in[2];
  const float* W     = (const float*)d_in[3];
  const float* bias  = (const float*)d_in[4];

  float* ws       = (float*)d_ws;
  float* Bpre     = ws;
  float* G        = ws + 393216;
  float* C        = ws + 393280;
  float* partials = ws + 393344;

  int k = (out_size - N_ROWS * N_EXP - 1) / N_ROWS;
  if (k < 1) k = 1;
  if (k > 4) k = 4;

  float* out      = (float*)d_out;
  float* out_sw   = out;
  float* out_idx  = out + (size_t)N_ROWS * N_EXP;
  float* out_loss = out + (size_t)N_ROWS * N_EXP + (size_t)N_ROWS * k;

  hipLaunchKernelGGL(prep_bpre, dim3(512), dim3(64), 0, stream, W, gamma, Bpre);
  hipLaunchKernelGGL(prep_gc, dim3(N_EXP), dim3(256), 0, stream, W, gamma, beta, bias, G, C);
  hipLaunchKernelGGL(router_main, dim3(NBLK), dim3(256), 0, stream,
                     x, Bpre, G, C, out_sw, out_idx, partials, k);
  hipLaunchKernelGGL(loss_kernel, dim3(1), dim3(256), 0, stream, partials, out_loss);
}